// Round 1
// baseline (707.618 us; speedup 1.0000x reference)
//
#include <hip/hip_runtime.h>
#include <hip/hip_fp16.h>
#include <cmath>

#define LNUM 6
#define DM   1152
#define DHEAD 256
#define NH   4
#define FF   6912
#define VOC  65536
#define HIST 4095
#define SEQ  4096
#define EPSV 1e-6f

// ---------------- helpers ----------------
__device__ __forceinline__ float block_reduce_sum256(float v, float* red) {
    int t = threadIdx.x;
    red[t] = v; __syncthreads();
    for (int off = 128; off > 0; off >>= 1) {
        if (t < off) red[t] += red[t + off];
        __syncthreads();
    }
    float r = red[0];
    __syncthreads();
    return r;
}

// ---------------- cache copies ----------------
__global__ __launch_bounds__(256) void gk_copy_keys(const float* __restrict__ kc,
                                                    float* __restrict__ keys) {
    int row = blockIdx.y;                       // 0 .. LNUM*DHEAD-1
    int s = blockIdx.x * 256 + threadIdx.x;
    if (s < HIST) keys[(size_t)row * SEQ + s] = kc[(size_t)row * HIST + s];
}

__global__ __launch_bounds__(256) void gk_copy_vals(const float* __restrict__ vc,
                                                    float* __restrict__ vals) {
    int r = blockIdx.x * 4 + (threadIdx.x >> 6); // row in 0..LNUM*HIST-1
    int d4 = threadIdx.x & 63;
    if (r < LNUM * HIST) {
        int l = r / HIST, s = r - l * HIST;
        const float4* src = (const float4*)(vc + (size_t)r * DHEAD);
        float4* dst = (float4*)(vals + ((size_t)l * SEQ + s) * DHEAD);
        dst[d4] = src[d4];
    }
}

// ---------------- embedding ----------------
__global__ __launch_bounds__(256) void gk_embed(const int* __restrict__ ids,
                                                const int* __restrict__ tbl,
                                                const float* __restrict__ scale,
                                                const float* __restrict__ zp,
                                                float* __restrict__ h0) {
    int tok = ids[0];
    float sc = scale[tok], z = zp[tok];
    const int* row = tbl + (size_t)tok * DM;
    for (int j = threadIdx.x; j < DM; j += 256) h0[j] = (float)row[j] * sc + z;
}

// ---------------- fused (prev-layer residual + input RMS) + QKV GEMV ----------------
__global__ __launch_bounds__(256) void gk_qkv(
    const float* __restrict__ Wq, const float* __restrict__ Wk, const float* __restrict__ Wv,
    const float* __restrict__ w_in, const float* __restrict__ w_pof_prev,
    const float* __restrict__ hprev,   // l==0: HIN(0) ; else HMID(l-1)
    const float* __restrict__ dprev,   // DPROJ(l-1) (unused when has_prev==0)
    float* __restrict__ hin_out,       // HIN(l)
    float* __restrict__ qkv_out,       // QKV(l) (zeroed)
    int has_prev, int ichunk) {
    __shared__ float xv[DM];
    __shared__ float red[256];
    int t = threadIdx.x;

    if (has_prev) {
        float ss = 0.f;
        for (int i = t; i < DM; i += 256) { float d = dprev[i]; ss += d * d; }
        ss = block_reduce_sum256(ss, red);
        float inv = 1.0f / sqrtf(ss / DM + EPSV);
        for (int i = t; i < DM; i += 256)
            xv[i] = hprev[i] + w_pof_prev[i] * dprev[i] * inv;
        __syncthreads();
        if (blockIdx.x == 0 && blockIdx.y == 0)
            for (int i = t; i < DM; i += 256) hin_out[i] = xv[i];
    } else {
        for (int i = t; i < DM; i += 256) xv[i] = hprev[i];
        __syncthreads();
    }
    float ss = 0.f;
    for (int i = t; i < DM; i += 256) { float v = xv[i]; ss += v * v; }
    ss = block_reduce_sum256(ss, red);
    float inv = 1.0f / sqrtf(ss / DM + EPSV);
    for (int i = t; i < DM; i += 256) xv[i] = w_in[i] * xv[i] * inv;
    __syncthreads();

    int j = blockIdx.x * 256 + t;  // 0..1535
    const float* W; int jj, ncol;
    if (j < 1024)      { W = Wq; jj = j;        ncol = NH * DHEAD; }
    else if (j < 1280) { W = Wk; jj = j - 1024; ncol = DHEAD; }
    else               { W = Wv; jj = j - 1280; ncol = DHEAD; }
    int i0 = blockIdx.y * ichunk;
    float acc = 0.f;
#pragma unroll 4
    for (int ii = 0; ii < ichunk; ++ii)
        acc += xv[i0 + ii] * W[(size_t)(i0 + ii) * ncol + jj];
    atomicAdd(&qkv_out[j], acc);
}

// ---------------- q/k RMS + RoPE + write new k,v ----------------
__global__ __launch_bounds__(256) void gk_qkprep(
    const float* __restrict__ qkv, const float* __restrict__ w_qn,
    const float* __restrict__ w_kn, float* __restrict__ qrope,
    float* __restrict__ keys_l,    // &keys[l*DHEAD*SEQ]
    float* __restrict__ vrow,      // &vals[(l*SEQ+HIST)*DHEAD]
    float rope_base) {
    __shared__ float lq[NH * DHEAD];
    __shared__ float lk[DHEAD];
    __shared__ float red[256];
    int t = threadIdx.x;
    for (int i = t; i < NH * DHEAD; i += 256) lq[i] = qkv[i];
    lk[t] = qkv[NH * DHEAD + t];
    __syncthreads();
    for (int h = 0; h < NH; ++h) {
        float v = lq[h * DHEAD + t];
        float ss = block_reduce_sum256(v * v, red);
        float inv = 1.f / sqrtf(ss / DHEAD + EPSV);
        lq[h * DHEAD + t] = w_qn[t] * v * inv;
    }
    {
        float v = lk[t];
        float ss = block_reduce_sum256(v * v, red);
        float inv = 1.f / sqrtf(ss / DHEAD + EPSV);
        lk[t] = w_kn[t] * v * inv;
    }
    __syncthreads();
    int jm = t & 127;
    float ex = -(float)(2 * jm) / 256.0f;
    float theta = powf(rope_base, ex);
    float ang = (float)HIST * theta;
    float c = __half2float(__float2half(cosf(ang)));
    float s = __half2float(__float2half(sinf(ang)));
    for (int h = 0; h < NH; ++h) {
        float x = lq[h * DHEAD + t];
        float xr = (t < 128) ? -lq[h * DHEAD + t + 128] : lq[h * DHEAD + t - 128];
        qrope[h * DHEAD + t] = x * c + xr * s;
    }
    float kx = lk[t];
    float kr = (t < 128) ? -lk[t + 128] : lk[t - 128];
    keys_l[(size_t)t * SEQ + (SEQ - 1)] = kx * c + kr * s;
    vrow[t] = qkv[NH * DHEAD + DHEAD + t];
}

// ---------------- scores = q . K  (+ mask) ----------------
__global__ __launch_bounds__(256) void gk_scores(const float* __restrict__ qrope,
                                                 const float* __restrict__ keys_l,
                                                 const int* __restrict__ attn_flag,
                                                 float* __restrict__ scores) {
    __shared__ float q[NH * DHEAD];
    __shared__ float red[NH * 256];
    int t = threadIdx.x;
    for (int i = t; i < NH * DHEAD; i += 256) q[i] = qrope[i];
    __syncthreads();
    int sl = t & 63, dc = t >> 6;
    int s = blockIdx.x * 64 + sl;
    float acc[NH] = {0.f, 0.f, 0.f, 0.f};
    for (int dd = 0; dd < 64; ++dd) {
        int d = dc * 64 + dd;
        float kv = keys_l[(size_t)d * SEQ + s];
#pragma unroll
        for (int h = 0; h < NH; ++h) acc[h] += q[h * DHEAD + d] * kv;
    }
#pragma unroll
    for (int h = 0; h < NH; ++h) red[h * 256 + t] = acc[h];
    __syncthreads();
    if (dc == 0) {
        float mk = (s > 0) ? (-128.0f * (float)attn_flag[0]) : 0.0f;
        for (int h = 0; h < NH; ++h) {
            float v = red[h * 256 + sl] + red[h * 256 + 64 + sl] +
                      red[h * 256 + 128 + sl] + red[h * 256 + 192 + sl];
            scores[h * SEQ + s] = v + mk;
        }
    }
}

// ---------------- softmax per head ----------------
__global__ __launch_bounds__(256) void gk_softmax(const float* __restrict__ scores,
                                                  float* __restrict__ probs) {
    __shared__ float red[256];
    int h = blockIdx.x, t = threadIdx.x;
    const float* sc = scores + h * SEQ;
    float* pr = probs + h * SEQ;
    float m = -1e30f;
    for (int s = t; s < SEQ; s += 256) m = fmaxf(m, sc[s]);
    red[t] = m; __syncthreads();
    for (int off = 128; off > 0; off >>= 1) {
        if (t < off) red[t] = fmaxf(red[t], red[t + off]);
        __syncthreads();
    }
    m = red[0]; __syncthreads();
    float sum = 0.f;
    for (int s = t; s < SEQ; s += 256) { float e = expf(sc[s] - m); pr[s] = e; sum += e; }
    sum = block_reduce_sum256(sum, red);
    float inv = 1.f / sum;
    for (int s = t; s < SEQ; s += 256) pr[s] *= inv;
}

// ---------------- attn_out = P . V ----------------
__global__ __launch_bounds__(256) void gk_pv(const float* __restrict__ probs,
                                             const float* __restrict__ vals_l,
                                             float* __restrict__ ao) {
    __shared__ float p[NH * 64];
    int t = threadIdx.x;
    int s0 = blockIdx.x * 64;
    { int h = t >> 6, ss = t & 63; p[h * 64 + ss] = probs[h * SEQ + s0 + ss]; }
    __syncthreads();
    float acc[NH] = {0.f, 0.f, 0.f, 0.f};
    for (int ss = 0; ss < 64; ++ss) {
        float v = vals_l[(size_t)(s0 + ss) * DHEAD + t];
#pragma unroll
        for (int h = 0; h < NH; ++h) acc[h] += p[h * 64 + ss] * v;
    }
#pragma unroll
    for (int h = 0; h < NH; ++h) atomicAdd(&ao[h * DHEAD + t], acc[h]);
}

// ---------------- ao @ Wo ----------------
__global__ __launch_bounds__(256) void gk_wo(const float* __restrict__ ao,
                                             const float* __restrict__ Wo_l,
                                             float* __restrict__ aproj, int ichunk) {
    __shared__ float x[64];
    int t = threadIdx.x;
    int i0 = blockIdx.y * ichunk;
    if (t < ichunk) x[t] = ao[i0 + t];
    __syncthreads();
    int j = blockIdx.x * 256 + t;
    if (j < DM) {
        float acc = 0.f;
#pragma unroll 4
        for (int ii = 0; ii < ichunk; ++ii)
            acc += x[ii] * Wo_l[(size_t)(i0 + ii) * DM + j];
        atomicAdd(&aproj[j], acc);
    }
}

// ---------------- fused (attn residual + pre-FFN RMS) + G/U GEMV ----------------
__global__ __launch_bounds__(256) void gk_gu(
    const float* __restrict__ Wg_l, const float* __restrict__ Wu_l,
    const float* __restrict__ w_pa, const float* __restrict__ w_pf,
    const float* __restrict__ hin, const float* __restrict__ aproj,
    float* __restrict__ hmid_out, float* __restrict__ gu, int ichunk) {
    __shared__ float xv[DM];
    __shared__ float red[256];
    int t = threadIdx.x;
    float ss = 0.f;
    for (int i = t; i < DM; i += 256) { float a = aproj[i]; ss += a * a; }
    ss = block_reduce_sum256(ss, red);
    float inv = 1.f / sqrtf(ss / DM + EPSV);
    for (int i = t; i < DM; i += 256) xv[i] = hin[i] + w_pa[i] * aproj[i] * inv;
    __syncthreads();
    if (blockIdx.x == 0 && blockIdx.y == 0)
        for (int i = t; i < DM; i += 256) hmid_out[i] = xv[i];
    float ss2 = 0.f;
    for (int i = t; i < DM; i += 256) { float v = xv[i]; ss2 += v * v; }
    ss2 = block_reduce_sum256(ss2, red);
    float inv2 = 1.f / sqrtf(ss2 / DM + EPSV);
    for (int i = t; i < DM; i += 256) xv[i] = w_pf[i] * xv[i] * inv2;
    __syncthreads();

    int j2 = blockIdx.x * 256 + t;     // float2 column, 0..6911
    const float2* W2; float* dst;
    int jj2;
    if (j2 < FF / 2) { W2 = (const float2*)Wg_l; jj2 = j2;           dst = gu + 2 * j2; }
    else             { W2 = (const float2*)Wu_l; jj2 = j2 - FF / 2;  dst = gu + FF + 2 * (j2 - FF / 2); }
    int i0 = blockIdx.y * ichunk;
    float ax = 0.f, ay = 0.f;
#pragma unroll 4
    for (int ii = 0; ii < ichunk; ++ii) {
        float xs = xv[i0 + ii];
        float2 w = W2[(size_t)(i0 + ii) * (FF / 2) + jj2];
        ax += xs * w.x; ay += xs * w.y;
    }
    atomicAdd(&dst[0], ax);
    atomicAdd(&dst[1], ay);
}

// ---------------- fused gelu(g)*u + Wd GEMV ----------------
__global__ __launch_bounds__(256) void gk_wd(const float* __restrict__ gu,
                                             const float* __restrict__ Wd_l,
                                             float* __restrict__ dproj, int ichunk) {
    __shared__ float m[128];
    int t = threadIdx.x;
    int i0 = blockIdx.y * ichunk;
    if (t < ichunk) {
        float g = gu[i0 + t], u = gu[FF + i0 + t];
        float gl = 0.5f * g * (1.f + tanhf(0.7978845608028654f * (g + 0.044715f * g * g * g)));
        m[t] = gl * u;
    }
    __syncthreads();
    int j = blockIdx.x * 256 + t;
    if (j < DM) {
        float acc = 0.f;
#pragma unroll 4
        for (int ii = 0; ii < ichunk; ++ii)
            acc += m[ii] * Wd_l[(size_t)(i0 + ii) * DM + j];
        atomicAdd(&dproj[j], acc);
    }
}

// ---------------- fused (ffn residual + final RMS) + LM-head GEMV ----------------
__global__ __launch_bounds__(256) void gk_logits(
    const float* __restrict__ W_lm, const float* __restrict__ w_pof5,
    const float* __restrict__ w_fin, const float* __restrict__ hmid5,
    const float* __restrict__ dproj5, float* __restrict__ logits, int ichunk) {
    __shared__ float xv[DM];
    __shared__ float red[256];
    int t = threadIdx.x;
    float ss = 0.f;
    for (int i = t; i < DM; i += 256) { float d = dproj5[i]; ss += d * d; }
    ss = block_reduce_sum256(ss, red);
    float inv = 1.f / sqrtf(ss / DM + EPSV);
    for (int i = t; i < DM; i += 256) xv[i] = hmid5[i] + w_pof5[i] * dproj5[i] * inv;
    __syncthreads();
    float ss2 = 0.f;
    for (int i = t; i < DM; i += 256) { float v = xv[i]; ss2 += v * v; }
    ss2 = block_reduce_sum256(ss2, red);
    float inv2 = 1.f / sqrtf(ss2 / DM + EPSV);
    for (int i = t; i < DM; i += 256) xv[i] = w_fin[i] * xv[i] * inv2;
    __syncthreads();

    int j2 = blockIdx.x * 256 + t;  // float2 column, 0..32767
    int i0 = blockIdx.y * ichunk;
    const float2* W2 = (const float2*)W_lm;
    float ax = 0.f, ay = 0.f;
#pragma unroll 4
    for (int ii = 0; ii < ichunk; ++ii) {
        float xs = xv[i0 + ii];
        float2 w = W2[(size_t)(i0 + ii) * (VOC / 2) + j2];
        ax += xs * w.x; ay += xs * w.y;
    }
    atomicAdd(&logits[2 * j2], ax);
    atomicAdd(&logits[2 * j2 + 1], ay);
}

// ---------------- argmax ----------------
__global__ __launch_bounds__(256) void gk_amax1(const float* __restrict__ logits,
                                                float* __restrict__ pv, float* __restrict__ pi) {
    __shared__ float rv[256];
    __shared__ int ri[256];
    int t = threadIdx.x;
    int base = blockIdx.x * 512;
    float v1 = logits[base + t], v2 = logits[base + 256 + t];
    float bv; int bi;
    if (v1 >= v2) { bv = v1; bi = base + t; } else { bv = v2; bi = base + 256 + t; }
    rv[t] = bv; ri[t] = bi; __syncthreads();
    for (int off = 128; off > 0; off >>= 1) {
        if (t < off) {
            float ov = rv[t + off]; int oi = ri[t + off];
            if (ov > rv[t] || (ov == rv[t] && oi < ri[t])) { rv[t] = ov; ri[t] = oi; }
        }
        __syncthreads();
    }
    if (t == 0) { pv[blockIdx.x] = rv[0]; pi[blockIdx.x] = (float)ri[0]; }
}

__global__ __launch_bounds__(128) void gk_amax2(const float* __restrict__ pv,
                                                const float* __restrict__ pi,
                                                float* __restrict__ tok_out) {
    __shared__ float rv[128];
    __shared__ int ri[128];
    int t = threadIdx.x;
    rv[t] = pv[t]; ri[t] = (int)pi[t]; __syncthreads();
    for (int off = 64; off > 0; off >>= 1) {
        if (t < off) {
            float ov = rv[t + off]; int oi = ri[t + off];
            if (ov > rv[t] || (ov == rv[t] && oi < ri[t])) { rv[t] = ov; ri[t] = oi; }
        }
        __syncthreads();
    }
    if (t == 0) tok_out[0] = (float)ri[0];
}

// ---------------- host launcher ----------------
extern "C" void kernel_launch(void* const* d_in, const int* in_sizes, int n_in,
                              void* d_out, int out_size, void* d_ws, size_t ws_size,
                              hipStream_t stream) {
    const int*   input_ids   = (const int*)d_in[0];
    const int*   attn_flag   = (const int*)d_in[1];
    const float* key_cache   = (const float*)d_in[2];
    const float* value_cache = (const float*)d_in[3];
    const int*   embed_table = (const int*)d_in[4];
    const float* embed_scale = (const float*)d_in[5];
    const float* embed_zp    = (const float*)d_in[6];
    const float* w_in_ln     = (const float*)d_in[7];
    const float* w_q_norm    = (const float*)d_in[8];
    const float* w_k_norm    = (const float*)d_in[9];
    const float* Wq          = (const float*)d_in[10];
    const float* Wk          = (const float*)d_in[11];
    const float* Wv          = (const float*)d_in[12];
    const float* Wo          = (const float*)d_in[13];
    const float* w_pa        = (const float*)d_in[14];
    const float* w_pf        = (const float*)d_in[15];
    const float* w_pof       = (const float*)d_in[16];
    const float* Wg          = (const float*)d_in[17];
    const float* Wu          = (const float*)d_in[18];
    const float* Wd          = (const float*)d_in[19];
    const float* w_fin       = (const float*)d_in[20];
    const float* W_lm        = (const float*)d_in[21];

    float* keys = (float*)d_out;                          // [L][1][D][SEQ]
    float* vals = keys + (size_t)LNUM * DHEAD * SEQ;      // [L][1][SEQ][D]
    float* tok_out = vals + (size_t)LNUM * SEQ * DHEAD;   // 1 float

    float* ws = (float*)d_ws;
    // accumulator region (zeroed each launch)
    const size_t QKV_O = 0;                                   // [L][1536]
    const size_t SC_O  = QKV_O + (size_t)LNUM * 1536;         // [L][NH*SEQ]
    const size_t AO_O  = SC_O + (size_t)LNUM * NH * SEQ;      // [L][NH*DHEAD]
    const size_t AP_O  = AO_O + (size_t)LNUM * NH * DHEAD;    // [L][DM]
    const size_t GU_O  = AP_O + (size_t)LNUM * DM;            // [L][2*FF]
    const size_t DP_O  = GU_O + (size_t)LNUM * 2 * FF;        // [L][DM]
    const size_t LG_O  = DP_O + (size_t)LNUM * DM;            // [VOC]
    const size_t ACC_END = LG_O + VOC;
    // non-accumulator scratch
    const size_t HIN_O = ACC_END;                             // [L][DM]
    const size_t HM_O  = HIN_O + (size_t)LNUM * DM;           // [L][DM]
    const size_t QR_O  = HM_O + (size_t)LNUM * DM;            // [L][NH*DHEAD]
    const size_t PR_O  = QR_O + (size_t)LNUM * NH * DHEAD;    // [L][NH*SEQ]
    const size_t AMV_O = PR_O + (size_t)LNUM * NH * SEQ;      // [128]
    const size_t AMI_O = AMV_O + 128;                         // [128]

    hipMemsetAsync(ws, 0, ACC_END * sizeof(float), stream);

    gk_copy_keys<<<dim3(16, LNUM * DHEAD), 256, 0, stream>>>(key_cache, keys);
    gk_copy_vals<<<(LNUM * HIST + 3) / 4, 256, 0, stream>>>(value_cache, vals);
    gk_embed<<<1, 256, 0, stream>>>(input_ids, embed_table, embed_scale, embed_zp, ws + HIN_O);

    for (int l = 0; l < LNUM; ++l) {
        float* QKVl = ws + QKV_O + (size_t)l * 1536;
        float* SCl  = ws + SC_O + (size_t)l * NH * SEQ;
        float* AOl  = ws + AO_O + (size_t)l * NH * DHEAD;
        float* APl  = ws + AP_O + (size_t)l * DM;
        float* GUl  = ws + GU_O + (size_t)l * 2 * FF;
        float* DPl  = ws + DP_O + (size_t)l * DM;
        float* HINl = ws + HIN_O + (size_t)l * DM;
        float* HMl  = ws + HM_O + (size_t)l * DM;
        float* QRl  = ws + QR_O + (size_t)l * NH * DHEAD;
        float* PRl  = ws + PR_O + (size_t)l * NH * SEQ;
        float* keys_l = keys + (size_t)l * DHEAD * SEQ;
        float* vals_l = vals + (size_t)l * SEQ * DHEAD;

        gk_qkv<<<dim3(6, 12), 256, 0, stream>>>(
            Wq + (size_t)l * DM * NH * DHEAD, Wk + (size_t)l * DM * DHEAD,
            Wv + (size_t)l * DM * DHEAD, w_in_ln + (size_t)l * DM,
            (l ? w_pof + (size_t)(l - 1) * DM : w_in_ln),
            (l ? ws + HM_O + (size_t)(l - 1) * DM : ws + HIN_O),
            (l ? ws + DP_O + (size_t)(l - 1) * DM : ws + HIN_O),
            HINl, QKVl, (l > 0) ? 1 : 0, 96);

        gk_qkprep<<<1, 256, 0, stream>>>(
            QKVl, w_q_norm + (size_t)l * DHEAD, w_k_norm + (size_t)l * DHEAD,
            QRl, keys_l, vals_l + (size_t)HIST * DHEAD,
            ((l % 6) != 5) ? 1000000.0f : 10000.0f);

        gk_scores<<<64, 256, 0, stream>>>(QRl, keys_l, attn_flag, SCl);
        gk_softmax<<<NH, 256, 0, stream>>>(SCl, PRl);
        gk_pv<<<64, 256, 0, stream>>>(PRl, vals_l, AOl);

        gk_wo<<<dim3(5, 16), 256, 0, stream>>>(AOl, Wo + (size_t)l * NH * DHEAD * DM, APl, 64);

        gk_gu<<<dim3(27, 16), 256, 0, stream>>>(
            Wg + (size_t)l * DM * FF, Wu + (size_t)l * DM * FF,
            w_pa + (size_t)l * DM, w_pf + (size_t)l * DM, HINl, APl, HMl, GUl, 72);

        gk_wd<<<dim3(5, 64), 256, 0, stream>>>(GUl, Wd + (size_t)l * FF * DM, DPl, 108);
    }

    gk_logits<<<dim3(128, 4), 256, 0, stream>>>(
        W_lm, w_pof + (size_t)5 * DM, w_fin,
        ws + HM_O + (size_t)5 * DM, ws + DP_O + (size_t)5 * DM, ws + LG_O, 288);
    gk_amax1<<<128, 256, 0, stream>>>(ws + LG_O, ws + AMV_O, ws + AMI_O);
    gk_amax2<<<1, 128, 0, stream>>>(ws + AMV_O, ws + AMI_O, tok_out);
}

// Round 2
// 596.006 us; speedup vs baseline: 1.1873x; 1.1873x over previous
//
#include <hip/hip_runtime.h>
#include <hip/hip_fp16.h>
#include <cmath>

#define LNUM 6
#define DM   1152
#define DHEAD 256
#define NH   4
#define FF   6912
#define VOC  65536
#define HIST 4095
#define SEQ  4096
#define EPSV 1e-6f

// shuffle-based block reduction over 256 threads (4 waves), 2 barriers
__device__ __forceinline__ float block_sum(float v, float* red4) {
#pragma unroll
    for (int off = 32; off; off >>= 1) v += __shfl_xor(v, off);
    int t = threadIdx.x;
    if ((t & 63) == 0) red4[t >> 6] = v;
    __syncthreads();
    float r = red4[0] + red4[1] + red4[2] + red4[3];
    __syncthreads();
    return r;
}

// ---------------- fused cache copies ----------------
// blocks [0, 24576): keys  (1536 rows x 4095, scalar)
// blocks [24576, 30720): vals (24570 rows x 256, float4, 4 rows/block)
__global__ __launch_bounds__(256) void gk_copy(const float* __restrict__ kc,
                                               const float* __restrict__ vc,
                                               float* __restrict__ keys,
                                               float* __restrict__ vals) {
    int b = blockIdx.x;
    if (b < 24576) {
        int row = b >> 4;
        int s = ((b & 15) << 8) + threadIdx.x;
        if (s < HIST) keys[(size_t)row * SEQ + s] = kc[(size_t)row * HIST + s];
    } else {
        int r = (b - 24576) * 4 + (threadIdx.x >> 6);
        int d4 = threadIdx.x & 63;
        if (r < LNUM * HIST) {
            int l = r / HIST, sI = r - l * HIST;
            ((float4*)(vals + ((size_t)l * SEQ + sI) * DHEAD))[d4] =
                ((const float4*)(vc + (size_t)r * DHEAD))[d4];
        }
    }
}

// ---------------- fused (embed | residual+RMS) + QKV GEMV ----------------
__global__ __launch_bounds__(256) void gk_qkv(
    const float* __restrict__ Wq, const float* __restrict__ Wk, const float* __restrict__ Wv,
    const float* __restrict__ w_in, const float* __restrict__ w_pof_prev,
    const float* __restrict__ hprev, const float* __restrict__ dprev,
    const int* __restrict__ ids, const int* __restrict__ tbl,
    const float* __restrict__ escale, const float* __restrict__ ezp,
    float* __restrict__ hin_out, float* __restrict__ qkv_out, int has_prev) {
    __shared__ float xv[DM];
    __shared__ float red4[4];
    int t = threadIdx.x;
    if (has_prev) {
        float ss = 0.f;
        for (int i = t; i < DM; i += 256) { float d = dprev[i]; ss += d * d; }
        ss = block_sum(ss, red4);
        float inv = 1.f / sqrtf(ss / DM + EPSV);
        for (int i = t; i < DM; i += 256)
            xv[i] = hprev[i] + w_pof_prev[i] * dprev[i] * inv;
    } else {
        int tok = ids[0];
        float sc = escale[tok], z = ezp[tok];
        const int* row = tbl + (size_t)tok * DM;
        for (int i = t; i < DM; i += 256) xv[i] = (float)row[i] * sc + z;
    }
    __syncthreads();
    if (blockIdx.x == 0 && blockIdx.y == 0)
        for (int i = t; i < DM; i += 256) hin_out[i] = xv[i];
    float ss = 0.f;
    for (int i = t; i < DM; i += 256) { float v = xv[i]; ss += v * v; }
    ss = block_sum(ss, red4);
    float inv = 1.f / sqrtf(ss / DM + EPSV);
    for (int i = t; i < DM; i += 256) xv[i] = w_in[i] * xv[i] * inv;
    __syncthreads();

    int j = blockIdx.x * 256 + t;  // 0..1535
    const float* W; int jj, ncol;
    if (j < 1024)      { W = Wq; jj = j;        ncol = 1024; }
    else if (j < 1280) { W = Wk; jj = j - 1024; ncol = 256; }
    else               { W = Wv; jj = j - 1280; ncol = 256; }
    int i0 = blockIdx.y * 36;
    float acc = 0.f;
#pragma unroll 4
    for (int ii = 0; ii < 36; ++ii)
        acc += xv[i0 + ii] * W[(size_t)(i0 + ii) * ncol + jj];
    atomicAdd(&qkv_out[j], acc);
}

// ---------------- fused attention (qk norm+rope, scores, exp, PV partials) ----------------
__global__ __launch_bounds__(256) void gk_attn(
    const float* __restrict__ qkv, const float* __restrict__ w_qn,
    const float* __restrict__ w_kn, const int* __restrict__ attn_flag,
    float* __restrict__ keys_l, float* __restrict__ vals_l,
    float* __restrict__ po_part, float* __restrict__ sum_part, float rope_base) {
    __shared__ float lq[NH * DHEAD];
    __shared__ float lqf[NH * DHEAD];
    __shared__ float lkn[DHEAD];
    __shared__ float lkf[DHEAD];
    __shared__ float lv[DHEAD];
    __shared__ float lp[NH * 32];
    __shared__ float red4[4];
    int t = threadIdx.x;
    int s0 = blockIdx.x * 32;
    bool last = (blockIdx.x == gridDim.x - 1);

    int jm = t & 127;
    float theta = powf(rope_base, -(float)(2 * jm) / 256.f);
    float ang = 4095.f * theta;
    float c = __half2float(__float2half(cosf(ang)));
    float s = __half2float(__float2half(sinf(ang)));

    for (int h = 0; h < NH; ++h) lq[h * 256 + t] = qkv[h * 256 + t];
    lkn[t] = qkv[1024 + t];
    lv[t]  = qkv[1280 + t];
    __syncthreads();
    for (int h = 0; h < NH; ++h) {
        float v = lq[h * 256 + t];
        float ss = block_sum(v * v, red4);
        float inv = 1.f / sqrtf(ss / 256.f + EPSV);
        float qn = w_qn[t] * v * inv;
        lq[h * 256 + t] = qn;
        __syncthreads();
        float partner = (t < 128) ? -lq[h * 256 + t + 128] : lq[h * 256 + t - 128];
        lqf[h * 256 + t] = qn * c + partner * s;
    }
    {
        float v = lkn[t];
        float ss = block_sum(v * v, red4);
        float inv = 1.f / sqrtf(ss / 256.f + EPSV);
        float kn = w_kn[t] * v * inv;
        lkn[t] = kn;
        __syncthreads();
        float partner = (t < 128) ? -lkn[t + 128] : lkn[t - 128];
        lkf[t] = kn * c + partner * s;
    }
    __syncthreads();
    if (last) {
        keys_l[(size_t)t * SEQ + (SEQ - 1)] = lkf[t];
        vals_l[(size_t)(SEQ - 1) * DHEAD + t] = lv[t];
    }
    // scores: 32 s-positions per block, 8 d-chunks of 32
    int sl = t & 31, dc = t >> 5;
    int sg = s0 + sl;
    bool self = last && (sl == 31);
    float a0 = 0, a1 = 0, a2 = 0, a3 = 0;
#pragma unroll 4
    for (int dd = 0; dd < 32; ++dd) {
        int d = dc * 32 + dd;
        float kv = self ? lkf[d] : keys_l[(size_t)d * SEQ + sg];
        a0 += lqf[0 * 256 + d] * kv;
        a1 += lqf[1 * 256 + d] * kv;
        a2 += lqf[2 * 256 + d] * kv;
        a3 += lqf[3 * 256 + d] * kv;
    }
    __syncthreads();  // lq reusable
    lq[0 * 256 + t] = a0; lq[1 * 256 + t] = a1; lq[2 * 256 + t] = a2; lq[3 * 256 + t] = a3;
    __syncthreads();
    if (t < 32) {
        int af = attn_flag[0];
        float mk = (s0 + t > 0) ? -128.f * (float)af : 0.f;
        for (int h = 0; h < NH; ++h) {
            float sc_ = 0.f;
#pragma unroll
            for (int d8 = 0; d8 < 8; ++d8) sc_ += lq[h * 256 + d8 * 32 + t];
            lp[h * 32 + t] = expf(sc_ + mk);   // no max-sub: scores O(1), exact ratio in fp32
        }
    }
    __syncthreads();
    if (t < NH) {
        float su = 0.f;
        for (int i = 0; i < 32; ++i) su += lp[t * 32 + i];
        sum_part[blockIdx.x * NH + t] = su;
    }
    // PV partials
    float p0 = 0, p1 = 0, p2 = 0, p3 = 0;
#pragma unroll 4
    for (int ss_ = 0; ss_ < 32; ++ss_) {
        float v = (last && ss_ == 31) ? lv[t] : vals_l[(size_t)(s0 + ss_) * DHEAD + t];
        p0 += lp[0 * 32 + ss_] * v;
        p1 += lp[1 * 32 + ss_] * v;
        p2 += lp[2 * 32 + ss_] * v;
        p3 += lp[3 * 32 + ss_] * v;
    }
    float* po = po_part + (size_t)blockIdx.x * NH * DHEAD;
    po[0 * 256 + t] = p0; po[1 * 256 + t] = p1; po[2 * 256 + t] = p2; po[3 * 256 + t] = p3;
}

// ---------------- wo GEMV (reduces PV partials + softmax normalize in prefix) ----------------
__global__ __launch_bounds__(256) void gk_wo(
    const float* __restrict__ po_part, const float* __restrict__ sum_part,
    const float* __restrict__ Wo_l, float* __restrict__ aproj) {
    __shared__ float x[64];
    __shared__ float hinv[NH];
    __shared__ float red4[4];
    int t = threadIdx.x;
    for (int h = 0; h < NH; ++h) {
        float v = (t < 128) ? sum_part[t * NH + h] : 0.f;
        float tot = block_sum(v, red4);
        if (t == 0) hinv[h] = 1.f / tot;
    }
    __syncthreads();
    int i0 = blockIdx.y * 64;
    if (t < 64) {
        float a = 0.f;
#pragma unroll 8
        for (int b = 0; b < 128; ++b) a += po_part[(size_t)b * 1024 + i0 + t];
        x[t] = a * hinv[(i0 + t) >> 8];
    }
    __syncthreads();
    int j = blockIdx.x * 256 + t;
    if (j < DM) {
        float acc = 0.f;
#pragma unroll 4
        for (int ii = 0; ii < 64; ++ii)
            acc += x[ii] * Wo_l[(size_t)(i0 + ii) * DM + j];
        atomicAdd(&aproj[j], acc);
    }
}

// ---------------- fused (attn residual + pre-FFN RMS) + G/U GEMV (partial out) ----------------
__global__ __launch_bounds__(256) void gk_gu(
    const float* __restrict__ Wg_l, const float* __restrict__ Wu_l,
    const float* __restrict__ w_pa, const float* __restrict__ w_pf,
    const float* __restrict__ hin, const float* __restrict__ aproj,
    float* __restrict__ hmid_out, float* __restrict__ gup) {
    __shared__ float xv[DM];
    __shared__ float red4[4];
    int t = threadIdx.x;
    float ss = 0.f;
    for (int i = t; i < DM; i += 256) { float a = aproj[i]; ss += a * a; }
    ss = block_sum(ss, red4);
    float inv = 1.f / sqrtf(ss / DM + EPSV);
    for (int i = t; i < DM; i += 256) xv[i] = hin[i] + w_pa[i] * aproj[i] * inv;
    __syncthreads();
    if (blockIdx.x == 0 && blockIdx.y == 0)
        for (int i = t; i < DM; i += 256) hmid_out[i] = xv[i];
    float s2 = 0.f;
    for (int i = t; i < DM; i += 256) { float v = xv[i]; s2 += v * v; }
    s2 = block_sum(s2, red4);
    float inv2 = 1.f / sqrtf(s2 / DM + EPSV);
    for (int i = t; i < DM; i += 256) xv[i] = w_pf[i] * xv[i] * inv2;
    __syncthreads();

    int j2 = blockIdx.x * 256 + t;   // 0..6911 (float2 cols)
    const float2* W2; int jj2; float* dst;
    if (j2 < FF / 2) { W2 = (const float2*)Wg_l; jj2 = j2;
                       dst = gup + (size_t)blockIdx.y * 2 * FF + 2 * j2; }
    else             { W2 = (const float2*)Wu_l; jj2 = j2 - FF / 2;
                       dst = gup + (size_t)blockIdx.y * 2 * FF + FF + 2 * (j2 - FF / 2); }
    int i0 = blockIdx.y * 72;
    float ax = 0.f, ay = 0.f;
#pragma unroll 4
    for (int ii = 0; ii < 72; ++ii) {
        float xs = xv[i0 + ii];
        float2 w = W2[(size_t)(i0 + ii) * (FF / 2) + jj2];
        ax += xs * w.x; ay += xs * w.y;
    }
    dst[0] = ax; dst[1] = ay;
}

// ---------------- fused (reduce GU partials + gelu) + Wd GEMV ----------------
__global__ __launch_bounds__(256) void gk_wd(const float* __restrict__ gup,
                                             const float* __restrict__ Wd_l,
                                             float* __restrict__ dproj) {
    __shared__ float m[108];
    int t = threadIdx.x;
    int i0 = blockIdx.y * 108;
    if (t < 108) {
        float g = 0.f, u = 0.f;
#pragma unroll
        for (int p = 0; p < 16; ++p) {
            g += gup[(size_t)p * 2 * FF + i0 + t];
            u += gup[(size_t)p * 2 * FF + FF + i0 + t];
        }
        float gl = 0.5f * g * (1.f + tanhf(0.7978845608028654f * (g + 0.044715f * g * g * g)));
        m[t] = gl * u;
    }
    __syncthreads();
    int j = blockIdx.x * 256 + t;
    if (j < DM) {
        float acc = 0.f;
#pragma unroll 4
        for (int ii = 0; ii < 108; ++ii)
            acc += m[ii] * Wd_l[(size_t)(i0 + ii) * DM + j];
        atomicAdd(&dproj[j], acc);
    }
}

// ---------------- fused (ffn residual + final RMS) + LM-head GEMV (partial out) ----------------
__global__ __launch_bounds__(256) void gk_logits(
    const float* __restrict__ W_lm, const float* __restrict__ w_pof5,
    const float* __restrict__ w_fin, const float* __restrict__ hmid5,
    const float* __restrict__ dproj5, float* __restrict__ lgp) {
    __shared__ float xv[DM];
    __shared__ float red4[4];
    int t = threadIdx.x;
    float ss = 0.f;
    for (int i = t; i < DM; i += 256) { float d = dproj5[i]; ss += d * d; }
    ss = block_sum(ss, red4);
    float inv = 1.f / sqrtf(ss / DM + EPSV);
    for (int i = t; i < DM; i += 256) xv[i] = hmid5[i] + w_pof5[i] * dproj5[i] * inv;
    __syncthreads();
    float s2 = 0.f;
    for (int i = t; i < DM; i += 256) { float v = xv[i]; s2 += v * v; }
    s2 = block_sum(s2, red4);
    float inv2 = 1.f / sqrtf(s2 / DM + EPSV);
    for (int i = t; i < DM; i += 256) xv[i] = w_fin[i] * xv[i] * inv2;
    __syncthreads();

    int j2 = blockIdx.x * 256 + t;   // 0..32767
    int i0 = blockIdx.y * 192;
    const float2* W2 = (const float2*)W_lm;
    float ax = 0.f, ay = 0.f;
#pragma unroll 4
    for (int ii = 0; ii < 192; ++ii) {
        float xs = xv[i0 + ii];
        float2 w = W2[(size_t)(i0 + ii) * (VOC / 2) + j2];
        ax += xs * w.x; ay += xs * w.y;
    }
    float* dst = lgp + (size_t)blockIdx.y * VOC + 2 * j2;
    dst[0] = ax; dst[1] = ay;
}

// ---------------- argmax (sums logit partials inline) ----------------
__global__ __launch_bounds__(256) void gk_amax1(const float* __restrict__ lgp,
                                                float* __restrict__ pv, float* __restrict__ pi) {
    __shared__ float rv[256];
    __shared__ int ri[256];
    int t = threadIdx.x;
    int c1 = blockIdx.x * 512 + t, c2 = c1 + 256;
    float v1 = 0.f, v2 = 0.f;
#pragma unroll
    for (int p = 0; p < 6; ++p) {
        v1 += lgp[(size_t)p * VOC + c1];
        v2 += lgp[(size_t)p * VOC + c2];
    }
    float bv; int bi;
    if (v1 >= v2) { bv = v1; bi = c1; } else { bv = v2; bi = c2; }
    rv[t] = bv; ri[t] = bi; __syncthreads();
    for (int off = 128; off > 0; off >>= 1) {
        if (t < off) {
            float ov = rv[t + off]; int oi = ri[t + off];
            if (ov > rv[t] || (ov == rv[t] && oi < ri[t])) { rv[t] = ov; ri[t] = oi; }
        }
        __syncthreads();
    }
    if (t == 0) { pv[blockIdx.x] = rv[0]; pi[blockIdx.x] = (float)ri[0]; }
}

__global__ __launch_bounds__(128) void gk_amax2(const float* __restrict__ pv,
                                                const float* __restrict__ pi,
                                                float* __restrict__ tok_out) {
    __shared__ float rv[128];
    __shared__ int ri[128];
    int t = threadIdx.x;
    rv[t] = pv[t]; ri[t] = (int)pi[t]; __syncthreads();
    for (int off = 64; off > 0; off >>= 1) {
        if (t < off) {
            float ov = rv[t + off]; int oi = ri[t + off];
            if (ov > rv[t] || (ov == rv[t] && oi < ri[t])) { rv[t] = ov; ri[t] = oi; }
        }
        __syncthreads();
    }
    if (t == 0) tok_out[0] = (float)ri[0];
}

// ---------------- host launcher ----------------
extern "C" void kernel_launch(void* const* d_in, const int* in_sizes, int n_in,
                              void* d_out, int out_size, void* d_ws, size_t ws_size,
                              hipStream_t stream) {
    const int*   input_ids   = (const int*)d_in[0];
    const int*   attn_flag   = (const int*)d_in[1];
    const float* key_cache   = (const float*)d_in[2];
    const float* value_cache = (const float*)d_in[3];
    const int*   embed_table = (const int*)d_in[4];
    const float* embed_scale = (const float*)d_in[5];
    const float* embed_zp    = (const float*)d_in[6];
    const float* w_in_ln     = (const float*)d_in[7];
    const float* w_q_norm    = (const float*)d_in[8];
    const float* w_k_norm    = (const float*)d_in[9];
    const float* Wq          = (const float*)d_in[10];
    const float* Wk          = (const float*)d_in[11];
    const float* Wv          = (const float*)d_in[12];
    const float* Wo          = (const float*)d_in[13];
    const float* w_pa        = (const float*)d_in[14];
    const float* w_pf        = (const float*)d_in[15];
    const float* w_pof       = (const float*)d_in[16];
    const float* Wg          = (const float*)d_in[17];
    const float* Wu          = (const float*)d_in[18];
    const float* Wd          = (const float*)d_in[19];
    const float* w_fin       = (const float*)d_in[20];
    const float* W_lm        = (const float*)d_in[21];

    float* keys = (float*)d_out;                          // [L][1][D][SEQ]
    float* vals = keys + (size_t)LNUM * DHEAD * SEQ;      // [L][1][SEQ][D]
    float* tok_out = vals + (size_t)LNUM * SEQ * DHEAD;

    float* ws = (float*)d_ws;
    // zeroed (atomic) region
    const size_t QKV_O = 0;                               // [L][1536]
    const size_t AP_O  = QKV_O + (size_t)LNUM * 1536;     // [L][DM]
    const size_t DP_O  = AP_O + (size_t)LNUM * DM;        // [L][DM]
    const size_t ZEND  = DP_O + (size_t)LNUM * DM;        // 23040 floats
    // partial (fully-overwritten) region
    const size_t POP_O = ZEND;                            // [128][NH*DHEAD]
    const size_t SPS_O = POP_O + 128 * 1024;              // [128][NH]
    const size_t GUP_O = SPS_O + 128 * NH;                // [16][2*FF]
    const size_t LGP_O = GUP_O + (size_t)16 * 2 * FF;     // [6][VOC]
    const size_t HIN_O = LGP_O + (size_t)6 * VOC;         // [L][DM]
    const size_t HM_O  = HIN_O + (size_t)LNUM * DM;       // [L][DM]
    const size_t AMV_O = HM_O + (size_t)LNUM * DM;        // [128]
    const size_t AMI_O = AMV_O + 128;                     // [128]

    hipMemsetAsync(ws, 0, ZEND * sizeof(float), stream);
    gk_copy<<<24576 + 6144, 256, 0, stream>>>(key_cache, value_cache, keys, vals);

    for (int l = 0; l < LNUM; ++l) {
        float* QKVl = ws + QKV_O + (size_t)l * 1536;
        float* APl  = ws + AP_O + (size_t)l * DM;
        float* DPl  = ws + DP_O + (size_t)l * DM;
        float* HINl = ws + HIN_O + (size_t)l * DM;
        float* HMl  = ws + HM_O + (size_t)l * DM;
        float* keys_l = keys + (size_t)l * DHEAD * SEQ;
        float* vals_l = vals + (size_t)l * SEQ * DHEAD;

        gk_qkv<<<dim3(6, 32), 256, 0, stream>>>(
            Wq + (size_t)l * DM * 1024, Wk + (size_t)l * DM * 256,
            Wv + (size_t)l * DM * 256, w_in_ln + (size_t)l * DM,
            w_pof + (size_t)(l ? l - 1 : 0) * DM,
            (l ? ws + HM_O + (size_t)(l - 1) * DM : nullptr),
            (l ? ws + DP_O + (size_t)(l - 1) * DM : nullptr),
            input_ids, embed_table, embed_scale, embed_zp,
            HINl, QKVl, (l > 0) ? 1 : 0);

        gk_attn<<<128, 256, 0, stream>>>(
            QKVl, w_q_norm + (size_t)l * DHEAD, w_k_norm + (size_t)l * DHEAD,
            attn_flag, keys_l, vals_l, ws + POP_O, ws + SPS_O,
            ((l % 6) != 5) ? 1000000.0f : 10000.0f);

        gk_wo<<<dim3(5, 16), 256, 0, stream>>>(
            ws + POP_O, ws + SPS_O, Wo + (size_t)l * 1024 * DM, APl);

        gk_gu<<<dim3(27, 16), 256, 0, stream>>>(
            Wg + (size_t)l * DM * FF, Wu + (size_t)l * DM * FF,
            w_pa + (size_t)l * DM, w_pf + (size_t)l * DM, HINl, APl, HMl, ws + GUP_O);

        gk_wd<<<dim3(5, 64), 256, 0, stream>>>(ws + GUP_O, Wd + (size_t)l * FF * DM, DPl);
    }

    gk_logits<<<dim3(128, 6), 256, 0, stream>>>(
        W_lm, w_pof + (size_t)5 * DM, w_fin,
        ws + HM_O + (size_t)5 * DM, ws + DP_O + (size_t)5 * DM, ws + LGP_O);
    gk_amax1<<<128, 256, 0, stream>>>(ws + LGP_O, ws + AMV_O, ws + AMI_O);
    gk_amax2<<<1, 128, 0, stream>>>(ws + AMV_O, ws + AMI_O, tok_out);
}